// Round 4
// baseline (567.080 us; speedup 1.0000x reference)
//
#include <hip/hip_runtime.h>
#include <stdint.h>

// B=4, S=2048, H=16, Dh=64, model dim 1024. K,V inputs ignored (reference
// attends Q against itself).
#define S_LEN 2048
#define DH    64
#define NH    16
#define DM    1024
#define NBH   64
#define PP    40      // P-buffer pitch in halves (80 B = 20 banks -> 2-way, free)

typedef float    f32x4 __attribute__((ext_vector_type(4)));
typedef _Float16 half8 __attribute__((ext_vector_type(8)));
typedef _Float16 half4 __attribute__((ext_vector_type(4)));

#define GL_LDS_B128(g, l) \
  __builtin_amdgcn_global_load_lds((const __attribute__((address_space(1))) void*)(g), \
                                   (__attribute__((address_space(3))) void*)(l), 16, 0, 0)

// ---------- preprocess (R2-validated LDS version: coalesced reads AND QhT stores) ----------
__global__ __launch_bounds__(256) void preprocess_kernel(const float* __restrict__ Q,
                                                         _Float16* __restrict__ Qh,
                                                         _Float16* __restrict__ QhT) {
    __shared__ _Float16 T[DH * 68];   // [d][s] transpose tile, pitch 68 halves
    const int tid = threadIdx.x;
    const int st = blockIdx.x & 31;   // s-tile of 64
    const int bh = blockIdx.x >> 5;
    const int b = bh >> 4, h = bh & 15;
    const float* src = Q + (size_t)b * S_LEN * DM + (size_t)(st * 64) * DM + h * DH;
    _Float16* qh_dst = Qh + ((size_t)bh * S_LEN + st * 64) * DH;
    _Float16* qt_dst = QhT + (size_t)bh * DH * S_LEN + st * 64;

    #pragma unroll
    for (int i = 0; i < 4; ++i) {
        const int lin = i * 256 + tid;
        const int sr  = lin >> 4;             // 0..63
        const int d4  = (lin & 15) * 4;
        const float4 v = *(const float4*)(src + (size_t)sr * DM + d4);
        const half4 hv = { (_Float16)v.x, (_Float16)v.y, (_Float16)v.z, (_Float16)v.w };
        *(half4*)(qh_dst + sr * DH + d4) = hv;
        T[(d4 + 0) * 68 + sr] = hv[0];
        T[(d4 + 1) * 68 + sr] = hv[1];
        T[(d4 + 2) * 68 + sr] = hv[2];
        T[(d4 + 3) * 68 + sr] = hv[3];
    }
    __syncthreads();
    #pragma unroll
    for (int i = 0; i < 4; ++i) {
        const int lin = i * 256 + tid;
        const int d   = lin >> 4;
        const int s4  = (lin & 15) * 4;
        const half4 tv = *(const half4*)&T[d * 68 + s4];
        *(half4*)(qt_dst + (size_t)d * S_LEN + s4) = tv;
    }
}

// ---------- attention v4: K-split x2, 32-key tiles, 18 KB LDS, atomic combine ----------
// Grid: bi = bh(64) x qblk(16) x ks(2). Each WG: 128 q rows, keys ks*1024..+1023.
// S^T = K Q^T (A = Kn LDS, B = Q regs); P -> LDS (pitch 40); O += P V (B = Kt LDS).
// Epilogue: atomicAdd unnormalized O into out, l partials into lws.
__global__ __launch_bounds__(128, 4) void attn_v4_kernel(const _Float16* __restrict__ Qh,
                                                         const _Float16* __restrict__ QhT,
                                                         float* __restrict__ out,
                                                         float* __restrict__ lws) {
    __shared__ __align__(16) _Float16 KnS[32 * 64];   // [kj][d]  4 KB, xor-8 chunk swizzle
    __shared__ __align__(16) _Float16 KtS[64 * 32];   // [d][kj]  4 KB, xor ((d>>1)&3) swizzle
    __shared__ __align__(16) _Float16 Pb[128 * PP];   // P [q][kj0..31], pitch 40 -> 10 KB

    const int tid  = threadIdx.x;
    const int w    = tid >> 6;
    const int lane = tid & 63;
    const int quad = lane >> 4;
    const int l15  = lane & 15;
    const int xq   = l15 & 7;
    const int bi   = blockIdx.x;
    const int ks   = bi & 1;
    const int qblk = (bi >> 1) & 15;
    const int bh   = bi >> 5;
    const int q0   = qblk * 128 + w * 64;
    const int kb   = ks * (S_LEN / 2);     // key base

    const _Float16* qh_bh = Qh + (size_t)bh * S_LEN * DH;
    const _Float16* qt_bh = QhT + (size_t)bh * DH * S_LEN;

    // Q register fragments (B-operand of S^T): lane holds Q[q=nch*16+l15][d=quad*8+j (+32)]
    half8 qreg[4][2];
    #pragma unroll
    for (int nch = 0; nch < 4; ++nch) {
        const _Float16* p = qh_bh + (size_t)(q0 + nch * 16 + l15) * DH + quad * 8;
        qreg[nch][0] = *(const half8*)p;
        qreg[nch][1] = *(const half8*)(p + 32);
    }

    // fixed per-column m = qs*||q||^2 (validated R1-R3)
    const float qs = 0.18033688011112042f;   // log2(e)/sqrt(64)
    float m_c[4];
    #pragma unroll
    for (int nch = 0; nch < 4; ++nch) {
        float part = 0.f;
        #pragma unroll
        for (int s = 0; s < 2; ++s)
            #pragma unroll
            for (int j = 0; j < 8; ++j) { const float x = (float)qreg[nch][s][j]; part += x * x; }
        part += __shfl_xor(part, 16, 64);
        part += __shfl_xor(part, 32, 64);
        m_c[nch] = qs * part;
    }

    // staging addresses: Kn 256 chunks + Kt 256 chunks, 128 threads -> 4 each
    const _Float16* kn_src[2]; _Float16* kn_dst[2];
    const _Float16* kt_src[2]; _Float16* kt_dst[2];
    #pragma unroll
    for (int i = 0; i < 2; ++i) {
        const int chn = i * 128 + tid;                 // Kn chunk
        const int rown = chn >> 3, cn = chn & 7;       // row kj 0..31, 8 chunks of d
        kn_src[i] = qh_bh + (size_t)(kb + rown) * DH + ((cn ^ (rown & 7)) * 8);   // + t*32*DH
        kn_dst[i] = &KnS[chn * 8];
        const int cht = i * 128 + tid;                 // Kt chunk
        const int dt = cht >> 2, ct = cht & 3;         // row d 0..63, 4 chunks of kj
        kt_src[i] = qt_bh + (size_t)dt * S_LEN + kb + ((ct ^ ((dt >> 1) & 3)) * 8);  // + t*32
        kt_dst[i] = &KtS[cht * 8];
    }

    f32x4 O[4][4];
    #pragma unroll
    for (int a = 0; a < 4; ++a)
        #pragma unroll
        for (int n = 0; n < 4; ++n) O[a][n] = (f32x4){0.f, 0.f, 0.f, 0.f};
    float lsum[4] = {0.f, 0.f, 0.f, 0.f};
    _Float16* Pw = &Pb[w * 64 * PP];

    for (int t = 0; t < (S_LEN / 2) / 32; ++t) {
        __syncthreads();
        GL_LDS_B128(kn_src[0] + t * (32 * DH), kn_dst[0]);
        GL_LDS_B128(kn_src[1] + t * (32 * DH), kn_dst[1]);
        GL_LDS_B128(kt_src[0] + t * 32, kt_dst[0]);
        GL_LDS_B128(kt_src[1] + t * 32, kt_dst[1]);
        __syncthreads();

        // ---- S^T: 2 kj-chunks x 4 q-chunks ----
        #pragma unroll
        for (int mch = 0; mch < 2; ++mch) {
            const half8 a0 = *(const half8*)&KnS[(mch * 16 + l15) * 64 + ((quad ^ xq) * 8)];
            const half8 a1 = *(const half8*)&KnS[(mch * 16 + l15) * 64 + (((4 + quad) ^ xq) * 8)];
            #pragma unroll
            for (int nch = 0; nch < 4; ++nch) {
                f32x4 acc = (f32x4){0.f, 0.f, 0.f, 0.f};
                acc = __builtin_amdgcn_mfma_f32_16x16x32_f16(a0, qreg[nch][0], acc, 0, 0, 0);
                acc = __builtin_amdgcn_mfma_f32_16x16x32_f16(a1, qreg[nch][1], acc, 0, 0, 0);
                const float p0 = __builtin_amdgcn_exp2f(__builtin_fmaf(acc[0], qs, -m_c[nch]));
                const float p1 = __builtin_amdgcn_exp2f(__builtin_fmaf(acc[1], qs, -m_c[nch]));
                const float p2 = __builtin_amdgcn_exp2f(__builtin_fmaf(acc[2], qs, -m_c[nch]));
                const float p3 = __builtin_amdgcn_exp2f(__builtin_fmaf(acc[3], qs, -m_c[nch]));
                lsum[nch] += (p0 + p1) + (p2 + p3);
                const half4 hv = (half4){ (_Float16)p0, (_Float16)p1, (_Float16)p2, (_Float16)p3 };
                *(half4*)&Pw[(nch * 16 + l15) * PP + mch * 16 + quad * 4] = hv;
            }
        }

        // ---- O += P V (same-wave P: lgkmcnt only) ----
        half8 pf[4];
        #pragma unroll
        for (int a = 0; a < 4; ++a)
            pf[a] = *(const half8*)&Pw[(a * 16 + l15) * PP + quad * 8];
        #pragma unroll
        for (int nch = 0; nch < 4; ++nch) {
            const half8 vf = *(const half8*)&KtS[(nch * 16 + l15) * 32 + ((quad ^ ((l15 >> 1) & 3)) * 8)];
            #pragma unroll
            for (int a = 0; a < 4; ++a)
                O[a][nch] = __builtin_amdgcn_mfma_f32_16x16x32_f16(pf[a], vf, O[a][nch], 0, 0, 0);
        }
    }

    // ---- epilogue: atomic partial combine ----
    #pragma unroll
    for (int nch = 0; nch < 4; ++nch) {
        float l = lsum[nch];
        l += __shfl_xor(l, 16, 64);
        l += __shfl_xor(l, 32, 64);
        if (quad == 0)
            atomicAdd(&lws[(size_t)bh * S_LEN + q0 + nch * 16 + l15], l);
    }
    const int b = bh >> 4, h = bh & 15;
    float* ob = out + (size_t)b * S_LEN * DM + h * DH;
    #pragma unroll
    for (int a = 0; a < 4; ++a)
        #pragma unroll
        for (int nch = 0; nch < 4; ++nch)
            #pragma unroll
            for (int r = 0; r < 4; ++r)
                atomicAdd(&ob[(size_t)(q0 + a * 16 + quad * 4 + r) * DM + nch * 16 + l15], O[a][nch][r]);
}

// ---------- normalize: out /= l ----------
__global__ __launch_bounds__(256) void normalize_kernel(float* __restrict__ out,
                                                        const float* __restrict__ lws) {
    const int i4 = blockIdx.x * 256 + threadIdx.x;      // 2,097,152 float4s
    const size_t e = (size_t)i4 * 4;
    const int b = (int)(e >> 21);
    const int s = (int)(e >> 10) & 2047;
    const int h = (int)(e >> 6) & 15;
    const float inv = 1.0f / lws[(size_t)((b << 4) + h) * S_LEN + s];
    float4 v = ((float4*)out)[i4];
    v.x *= inv; v.y *= inv; v.z *= inv; v.w *= inv;
    ((float4*)out)[i4] = v;
}

// ---------- fallback: R3-validated single-pass kernel (no extra ws / atomics) ----------
__global__ __launch_bounds__(128, 2) void attn_v3_kernel(const _Float16* __restrict__ Qh,
                                                         const _Float16* __restrict__ QhT,
                                                         float* __restrict__ out) {
    __shared__ __align__(16) _Float16 KnS[64 * 64];
    __shared__ __align__(16) _Float16 KtS[64 * 64];
    __shared__ __align__(16) _Float16 Pb[2][64 * 64];
    const int tid = threadIdx.x;
    const int w = tid >> 6, lane = tid & 63, quad = lane >> 4, l15 = lane & 15;
    const int xq = l15 & 7;
    const int qblk = blockIdx.x & 15;
    const int bh = blockIdx.x >> 4;
    const int q0 = qblk * 128 + w * 64;
    const _Float16* qh_bh = Qh + (size_t)bh * S_LEN * DH;
    const _Float16* qt_bh = QhT + (size_t)bh * DH * S_LEN;
    half8 qreg[4][2];
    #pragma unroll
    for (int nch = 0; nch < 4; ++nch) {
        const _Float16* p = qh_bh + (size_t)(q0 + nch * 16 + l15) * DH + quad * 8;
        qreg[nch][0] = *(const half8*)p;
        qreg[nch][1] = *(const half8*)(p + 32);
    }
    const float qs = 0.18033688011112042f;
    float m_c[4];
    #pragma unroll
    for (int nch = 0; nch < 4; ++nch) {
        float part = 0.f;
        #pragma unroll
        for (int s = 0; s < 2; ++s)
            #pragma unroll
            for (int j = 0; j < 8; ++j) { const float x = (float)qreg[nch][s][j]; part += x * x; }
        part += __shfl_xor(part, 16, 64);
        part += __shfl_xor(part, 32, 64);
        m_c[nch] = qs * part;
    }
    const _Float16* kn_src[4]; _Float16* kn_dst[4];
    const _Float16* kt_src[4]; _Float16* kt_dst[4];
    #pragma unroll
    for (int i = 0; i < 4; ++i) {
        const int ch = i * 128 + tid;
        const int row = ch >> 3, c = ch & 7;
        kn_src[i] = qh_bh + row * DH + ((c ^ (row & 7)) * 8);
        kn_dst[i] = &KnS[ch * 8];
        kt_src[i] = qt_bh + (size_t)row * S_LEN + ((c ^ (row & 7)) * 8);
        kt_dst[i] = &KtS[ch * 8];
    }
    f32x4 O[4][4];
    #pragma unroll
    for (int m = 0; m < 4; ++m)
        #pragma unroll
        for (int n = 0; n < 4; ++n) O[m][n] = (f32x4){0.f, 0.f, 0.f, 0.f};
    float lsum[4] = {0.f, 0.f, 0.f, 0.f};
    _Float16* Pw = Pb[w];
    for (int t = 0; t < S_LEN / 64; ++t) {
        __syncthreads();
        #pragma unroll
        for (int i = 0; i < 4; ++i) GL_LDS_B128(kn_src[i] + t * (64 * DH), kn_dst[i]);
        #pragma unroll
        for (int i = 0; i < 4; ++i) GL_LDS_B128(kt_src[i] + t * 64, kt_dst[i]);
        __syncthreads();
        #pragma unroll
        for (int mch = 0; mch < 4; ++mch) {
            const half8 a0 = *(const half8*)&KnS[(mch * 16 + l15) * 64 + ((quad ^ xq) * 8)];
            const half8 a1 = *(const half8*)&KnS[(mch * 16 + l15) * 64 + (((4 + quad) ^ xq) * 8)];
            const int wc = 2 * mch + (quad >> 1);
            const int woff = (quad & 1) * 4;
            #pragma unroll
            for (int nch = 0; nch < 4; ++nch) {
                f32x4 acc = (f32x4){0.f, 0.f, 0.f, 0.f};
                acc = __builtin_amdgcn_mfma_f32_16x16x32_f16(a0, qreg[nch][0], acc, 0, 0, 0);
                acc = __builtin_amdgcn_mfma_f32_16x16x32_f16(a1, qreg[nch][1], acc, 0, 0, 0);
                const float p0 = __builtin_amdgcn_exp2f(__builtin_fmaf(acc[0], qs, -m_c[nch]));
                const float p1 = __builtin_amdgcn_exp2f(__builtin_fmaf(acc[1], qs, -m_c[nch]));
                const float p2 = __builtin_amdgcn_exp2f(__builtin_fmaf(acc[2], qs, -m_c[nch]));
                const float p3 = __builtin_amdgcn_exp2f(__builtin_fmaf(acc[3], qs, -m_c[nch]));
                lsum[nch] += (p0 + p1) + (p2 + p3);
                const half4 hv = (half4){ (_Float16)p0, (_Float16)p1, (_Float16)p2, (_Float16)p3 };
                *(half4*)&Pw[(nch * 16 + l15) * 64 + ((wc ^ xq) * 8) + woff] = hv;
            }
        }
        half8 pf[4][2];
        #pragma unroll
        for (int mch = 0; mch < 4; ++mch) {
            pf[mch][0] = *(const half8*)&Pw[(mch * 16 + l15) * 64 + ((quad ^ xq) * 8)];
            pf[mch][1] = *(const half8*)&Pw[(mch * 16 + l15) * 64 + (((4 + quad) ^ xq) * 8)];
        }
        #pragma unroll
        for (int nch = 0; nch < 4; ++nch) {
            const half8 v0 = *(const half8*)&KtS[(nch * 16 + l15) * 64 + ((quad ^ xq) * 8)];
            const half8 v1 = *(const half8*)&KtS[(nch * 16 + l15) * 64 + (((4 + quad) ^ xq) * 8)];
            #pragma unroll
            for (int mch = 0; mch < 4; ++mch) {
                O[mch][nch] = __builtin_amdgcn_mfma_f32_16x16x32_f16(pf[mch][0], v0, O[mch][nch], 0, 0, 0);
                O[mch][nch] = __builtin_amdgcn_mfma_f32_16x16x32_f16(pf[mch][1], v1, O[mch][nch], 0, 0, 0);
            }
        }
    }
    float lcol[4];
    #pragma unroll
    for (int nch = 0; nch < 4; ++nch) {
        float l = lsum[nch];
        l += __shfl_xor(l, 16, 64);
        l += __shfl_xor(l, 32, 64);
        lcol[nch] = l;
    }
    const int b = bh >> 4, h = bh & 15;
    float* ob = out + (size_t)b * S_LEN * DM + h * DH;
    #pragma unroll
    for (int mch = 0; mch < 4; ++mch) {
        float inv[4];
        #pragma unroll
        for (int r = 0; r < 4; ++r)
            inv[r] = 1.0f / __shfl(lcol[mch], quad * 4 + r, 16);
        #pragma unroll
        for (int nch = 0; nch < 4; ++nch)
            #pragma unroll
            for (int r = 0; r < 4; ++r)
                ob[(size_t)(q0 + mch * 16 + quad * 4 + r) * DM + nch * 16 + l15] = O[mch][nch][r] * inv[r];
    }
}

extern "C" void kernel_launch(void* const* d_in, const int* in_sizes, int n_in,
                              void* d_out, int out_size, void* d_ws, size_t ws_size,
                              hipStream_t stream) {
    const float* Q = (const float*)d_in[0];   // K, V ignored per reference
    float* out = (float*)d_out;
    const size_t qh_bytes = (size_t)NBH * S_LEN * DH * sizeof(_Float16);  // 16 MiB
    const size_t l_bytes  = (size_t)NBH * S_LEN * sizeof(float);          // 512 KiB
    _Float16* Qh  = (_Float16*)d_ws;
    _Float16* QhT = (_Float16*)((char*)d_ws + qh_bytes);
    preprocess_kernel<<<dim3(NBH * (S_LEN / 64)), dim3(256), 0, stream>>>(Q, Qh, QhT);

    if (ws_size >= 2 * qh_bytes + l_bytes) {
        float* lws = (float*)((char*)d_ws + 2 * qh_bytes);
        hipMemsetAsync(out, 0, (size_t)out_size * sizeof(float), stream);
        hipMemsetAsync(lws, 0, l_bytes, stream);
        attn_v4_kernel<<<dim3(NBH * 16 * 2), dim3(128), 0, stream>>>(Qh, QhT, out, lws);
        normalize_kernel<<<dim3((out_size / 4) / 256), dim3(256), 0, stream>>>(out, lws);
    } else {
        attn_v3_kernel<<<dim3(NBH * (S_LEN / 128)), dim3(128), 0, stream>>>(Qh, QhT, out);
    }
}

// Round 5
// 445.013 us; speedup vs baseline: 1.2743x; 1.2743x over previous
//
#include <hip/hip_runtime.h>
#include <stdint.h>

// B=4, S=2048, H=16, Dh=64, model dim 1024. K,V inputs ignored (reference
// attends Q against itself).
#define S_LEN 2048
#define DH    64
#define NH    16
#define DM    1024
#define NBH   64
#define PP    40      // P row pitch in halves (80 B = 20 banks -> 2-way, free)

typedef float    f32x4 __attribute__((ext_vector_type(4)));
typedef _Float16 half8 __attribute__((ext_vector_type(8)));
typedef _Float16 half4 __attribute__((ext_vector_type(4)));

#define GL_LDS_B128(g, l) \
  __builtin_amdgcn_global_load_lds((const __attribute__((address_space(1))) void*)(g), \
                                   (__attribute__((address_space(3))) void*)(l), 16, 0, 0)

// ---------- preprocess (R2-validated): fp32 Q -> f16 Qh [bh][s][d], QhT [bh][d][s] ----------
__global__ __launch_bounds__(256) void preprocess_kernel(const float* __restrict__ Q,
                                                         _Float16* __restrict__ Qh,
                                                         _Float16* __restrict__ QhT) {
    __shared__ _Float16 T[DH * 68];
    const int tid = threadIdx.x;
    const int st = blockIdx.x & 31;
    const int bh = blockIdx.x >> 5;
    const int b = bh >> 4, h = bh & 15;
    const float* src = Q + (size_t)b * S_LEN * DM + (size_t)(st * 64) * DM + h * DH;
    _Float16* qh_dst = Qh + ((size_t)bh * S_LEN + st * 64) * DH;
    _Float16* qt_dst = QhT + (size_t)bh * DH * S_LEN + st * 64;

    #pragma unroll
    for (int i = 0; i < 4; ++i) {
        const int lin = i * 256 + tid;
        const int sr  = lin >> 4;
        const int d4  = (lin & 15) * 4;
        const float4 v = *(const float4*)(src + (size_t)sr * DM + d4);
        const half4 hv = { (_Float16)v.x, (_Float16)v.y, (_Float16)v.z, (_Float16)v.w };
        *(half4*)(qh_dst + sr * DH + d4) = hv;
        T[(d4 + 0) * 68 + sr] = hv[0];
        T[(d4 + 1) * 68 + sr] = hv[1];
        T[(d4 + 2) * 68 + sr] = hv[2];
        T[(d4 + 3) * 68 + sr] = hv[3];
    }
    __syncthreads();
    #pragma unroll
    for (int i = 0; i < 4; ++i) {
        const int lin = i * 256 + tid;
        const int d   = lin >> 4;
        const int s4  = (lin & 15) * 4;
        const half4 tv = *(const half4*)&T[d * 68 + s4];
        *(half4*)(qt_dst + (size_t)d * S_LEN + s4) = tv;
    }
}

// ---------- attention v5: 4 waves = 2 q-blocks x 2 key-halves, in-LDS partial combine ----------
// Wave (p = w&1, ks = w>>1): q rows [qblk*128 + p*64, +64), keys [ks*1024, +1024), 32-key tiles.
// S^T = K Q^T (A = Kn LDS, B = Q regs) -> exp2 -> P LDS (pitch 40) -> O += P V (B = Kt LDS).
// Epilogue: ks=1 waves dump O (f16) + lsum into dead LDS; ks=0 waves combine, normalize, store.
__global__ __launch_bounds__(256, 4) void attn_v5_kernel(const _Float16* __restrict__ Qh,
                                                         const _Float16* __restrict__ QhT,
                                                         float* __restrict__ out) {
    __shared__ __align__(16) _Float16 stag[4 * 2048];   // KnA,KtA,KnB,KtB: 4 x 4 KB
    __shared__ __align__(16) _Float16 Pbuf[4 * 64 * PP]; // per-wave P [64 q][32 kj], 4 x 5 KB

    const int tid  = threadIdx.x;
    const int w    = tid >> 6;
    const int lane = tid & 63;
    const int quad = lane >> 4;
    const int l15  = lane & 15;
    const int xq   = l15 & 7;
    const int p    = w & 1;        // q-block pair
    const int ks   = w >> 1;       // key half
    const int qblk = blockIdx.x & 15;
    const int bh   = blockIdx.x >> 4;
    const int q0   = qblk * 128 + p * 64;

    const _Float16* qh_bh = Qh + (size_t)bh * S_LEN * DH;
    const _Float16* qt_bh = QhT + (size_t)bh * DH * S_LEN;

    // Q register fragments (B-operand of S^T): lane holds Q[q=nch*16+l15][d=sk*32+quad*8+j]
    half8 qreg[4][2];
    #pragma unroll
    for (int nch = 0; nch < 4; ++nch) {
        const _Float16* ptr = qh_bh + (size_t)(q0 + nch * 16 + l15) * DH + quad * 8;
        qreg[nch][0] = *(const half8*)ptr;
        qreg[nch][1] = *(const half8*)(ptr + 32);
    }

    // fixed per-column m = qs*||q||^2 (identical across key halves -> partials additive; validated R1-R4)
    const float qs = 0.18033688011112042f;   // log2(e)/sqrt(64)
    float m_c[4];
    #pragma unroll
    for (int nch = 0; nch < 4; ++nch) {
        float part = 0.f;
        #pragma unroll
        for (int s = 0; s < 2; ++s)
            #pragma unroll
            for (int j = 0; j < 8; ++j) { const float x = (float)qreg[nch][s][j]; part += x * x; }
        part += __shfl_xor(part, 16, 64);
        part += __shfl_xor(part, 32, 64);
        m_c[nch] = qs * part;
    }

    // staging: 4 buffers x 256 chunks of 16 B; thread tid stages LDS-linear chunk tid of each.
    // Kn buffer (32 kj x 64 d): chunk = row*8 + cp; data at phys cp comes from global col cp^(row&7).
    // Kt buffer (64 d x 32 kj): chunk = d*4 + cp;  data from global kj-chunk cp^((d>>1)&3).
    const int rown = tid >> 3, cn = tid & 7;
    const int dt   = tid >> 2, ct = tid & 3;
    const _Float16* kn_srcA = qh_bh + (size_t)rown * DH + ((cn ^ (rown & 7)) * 8);          // + kb*DH
    const _Float16* kt_srcA = qt_bh + (size_t)dt * S_LEN + ((ct ^ ((dt >> 1) & 3)) * 8);    // + kb
    _Float16* kn_dstA = &stag[0 * 2048 + tid * 8];
    _Float16* kt_dstA = &stag[1 * 2048 + tid * 8];
    _Float16* kn_dstB = &stag[2 * 2048 + tid * 8];
    _Float16* kt_dstB = &stag[3 * 2048 + tid * 8];

    const _Float16* KnW = &stag[(ks * 2) * 2048];       // this wave's Kn tile
    const _Float16* KtW = &stag[(ks * 2 + 1) * 2048];   // this wave's Kt tile
    _Float16* Pw = &Pbuf[w * 64 * PP];

    f32x4 O[4][4];
    #pragma unroll
    for (int a = 0; a < 4; ++a)
        #pragma unroll
        for (int n = 0; n < 4; ++n) O[a][n] = (f32x4){0.f, 0.f, 0.f, 0.f};
    float lsum[4] = {0.f, 0.f, 0.f, 0.f};

    for (int t = 0; t < 32; ++t) {
        const int kbA = t * 32;            // keys for pair-A waves
        const int kbB = 1024 + t * 32;     // keys for pair-B waves
        __syncthreads();                   // prior tile's LDS reads done
        GL_LDS_B128(kn_srcA + (size_t)kbA * DH, kn_dstA);
        GL_LDS_B128(kt_srcA + kbA,              kt_dstA);
        GL_LDS_B128(kn_srcA + (size_t)kbB * DH, kn_dstB);
        GL_LDS_B128(kt_srcA + kbB,              kt_dstB);
        __syncthreads();                   // drains vmcnt

        // ---- S^T: 2 kj-chunks (mch) x 4 q-chunks (nch), K=64 in 2 steps ----
        #pragma unroll
        for (int mch = 0; mch < 2; ++mch) {
            const half8 a0 = *(const half8*)&KnW[(mch * 16 + l15) * 64 + ((quad ^ xq) * 8)];
            const half8 a1 = *(const half8*)&KnW[(mch * 16 + l15) * 64 + (((4 + quad) ^ xq) * 8)];
            #pragma unroll
            for (int nch = 0; nch < 4; ++nch) {
                f32x4 acc = (f32x4){0.f, 0.f, 0.f, 0.f};
                acc = __builtin_amdgcn_mfma_f32_16x16x32_f16(a0, qreg[nch][0], acc, 0, 0, 0);
                acc = __builtin_amdgcn_mfma_f32_16x16x32_f16(a1, qreg[nch][1], acc, 0, 0, 0);
                const float p0 = __builtin_amdgcn_exp2f(__builtin_fmaf(acc[0], qs, -m_c[nch]));
                const float p1 = __builtin_amdgcn_exp2f(__builtin_fmaf(acc[1], qs, -m_c[nch]));
                const float p2 = __builtin_amdgcn_exp2f(__builtin_fmaf(acc[2], qs, -m_c[nch]));
                const float p3 = __builtin_amdgcn_exp2f(__builtin_fmaf(acc[3], qs, -m_c[nch]));
                lsum[nch] += (p0 + p1) + (p2 + p3);
                const half4 hv = (half4){ (_Float16)p0, (_Float16)p1, (_Float16)p2, (_Float16)p3 };
                *(half4*)&Pw[(nch * 16 + l15) * PP + mch * 16 + quad * 4] = hv;
            }
        }

        // ---- O += P V (same-wave P: lgkmcnt only; kj=32 -> single k-step) ----
        half8 pf[4];
        #pragma unroll
        for (int a = 0; a < 4; ++a)
            pf[a] = *(const half8*)&Pw[(a * 16 + l15) * PP + quad * 8];
        #pragma unroll
        for (int nch = 0; nch < 4; ++nch) {
            const half8 vf = *(const half8*)&KtW[(nch * 16 + l15) * 32 + ((quad ^ ((l15 >> 1) & 3)) * 8)];
            #pragma unroll
            for (int a = 0; a < 4; ++a)
                O[a][nch] = __builtin_amdgcn_mfma_f32_16x16x32_f16(pf[a], vf, O[a][nch], 0, 0, 0);
        }
    }

    // ---- in-LDS partial combine (no atomics, no extra global traffic) ----
    __syncthreads();                                      // all tile reads done; stag/Pbuf now dead
    _Float16* obx = stag;                                 // 2 pairs x 4096 halves (f16 O partials)
    float* lx = (float*)&Pbuf[2 * 64 * PP];               // 2 pairs x 256 floats (raw lsum partials)
    if (ks == 1) {
        #pragma unroll
        for (int a = 0; a < 4; ++a)
            #pragma unroll
            for (int nch = 0; nch < 4; ++nch)
                #pragma unroll
                for (int r = 0; r < 4; ++r)
                    obx[p * 4096 + (a * 16 + nch * 4 + r) * 64 + lane] = (_Float16)O[a][nch][r];
        #pragma unroll
        for (int nch = 0; nch < 4; ++nch)
            lx[p * 256 + nch * 64 + lane] = lsum[nch];
    }
    __syncthreads();
    if (ks == 0) {
        #pragma unroll
        for (int a = 0; a < 4; ++a)
            #pragma unroll
            for (int nch = 0; nch < 4; ++nch)
                #pragma unroll
                for (int r = 0; r < 4; ++r)
                    O[a][nch][r] += (float)obx[p * 4096 + (a * 16 + nch * 4 + r) * 64 + lane];
        #pragma unroll
        for (int nch = 0; nch < 4; ++nch)
            lsum[nch] += lx[p * 256 + nch * 64 + lane];

        float lcol[4];
        #pragma unroll
        for (int nch = 0; nch < 4; ++nch) {
            float l = lsum[nch];
            l += __shfl_xor(l, 16, 64);
            l += __shfl_xor(l, 32, 64);
            lcol[nch] = l;
        }
        const int b = bh >> 4, h = bh & 15;
        float* ob = out + (size_t)b * S_LEN * DM + h * DH;
        #pragma unroll
        for (int a = 0; a < 4; ++a) {
            float inv[4];
            #pragma unroll
            for (int r = 0; r < 4; ++r)
                inv[r] = 1.0f / __shfl(lcol[a], quad * 4 + r, 16);
            #pragma unroll
            for (int nch = 0; nch < 4; ++nch)
                #pragma unroll
                for (int r = 0; r < 4; ++r)
                    ob[(size_t)(q0 + a * 16 + quad * 4 + r) * DM + nch * 16 + l15] = O[a][nch][r] * inv[r];
        }
    }
}

extern "C" void kernel_launch(void* const* d_in, const int* in_sizes, int n_in,
                              void* d_out, int out_size, void* d_ws, size_t ws_size,
                              hipStream_t stream) {
    const float* Q = (const float*)d_in[0];   // K, V ignored per reference
    float* out = (float*)d_out;
    _Float16* Qh  = (_Float16*)d_ws;                      // 16 MiB
    _Float16* QhT = Qh + (size_t)NBH * S_LEN * DH;        // 16 MiB (ws >= 32 MiB verified R2/R3)
    preprocess_kernel<<<dim3(NBH * (S_LEN / 64)), dim3(256), 0, stream>>>(Q, Qh, QhT);
    attn_v5_kernel<<<dim3(NBH * (S_LEN / 128)), dim3(256), 0, stream>>>(Qh, QhT, out);
}

// Round 7
// 245.420 us; speedup vs baseline: 2.3106x; 1.8133x over previous
//
#include <hip/hip_runtime.h>
#include <stdint.h>

// B=4, S=2048, H=16, Dh=64, model dim 1024. K,V inputs ignored (reference
// attends Q against itself).
#define S_LEN 2048
#define DH    64
#define NH    16
#define DM    1024
#define NBH   64
#define PP    72      // P row pitch in halves: 144 B rows, 16B-aligned. MUST be >=64
                      // (kj spans 0..63 per row) — PP=40 here was the R6 corruption bug.

typedef float    f32x4 __attribute__((ext_vector_type(4)));
typedef _Float16 half8 __attribute__((ext_vector_type(8)));
typedef _Float16 half4 __attribute__((ext_vector_type(4)));

// ---------- preprocess (R2-validated): fp32 Q -> f16 Qh [bh][s][d], QhT [bh][d][s] ----------
__global__ __launch_bounds__(256) void preprocess_kernel(const float* __restrict__ Q,
                                                         _Float16* __restrict__ Qh,
                                                         _Float16* __restrict__ QhT) {
    __shared__ _Float16 T[DH * 68];
    const int tid = threadIdx.x;
    const int st = blockIdx.x & 31;
    const int bh = blockIdx.x >> 5;
    const int b = bh >> 4, h = bh & 15;
    const float* src = Q + (size_t)b * S_LEN * DM + (size_t)(st * 64) * DM + h * DH;
    _Float16* qh_dst = Qh + ((size_t)bh * S_LEN + st * 64) * DH;
    _Float16* qt_dst = QhT + (size_t)bh * DH * S_LEN + st * 64;

    #pragma unroll
    for (int i = 0; i < 4; ++i) {
        const int lin = i * 256 + tid;
        const int sr  = lin >> 4;
        const int d4  = (lin & 15) * 4;
        const float4 v = *(const float4*)(src + (size_t)sr * DM + d4);
        const half4 hv = { (_Float16)v.x, (_Float16)v.y, (_Float16)v.z, (_Float16)v.w };
        *(half4*)(qh_dst + sr * DH + d4) = hv;
        T[(d4 + 0) * 68 + sr] = hv[0];
        T[(d4 + 1) * 68 + sr] = hv[1];
        T[(d4 + 2) * 68 + sr] = hv[2];
        T[(d4 + 3) * 68 + sr] = hv[3];
    }
    __syncthreads();
    #pragma unroll
    for (int i = 0; i < 4; ++i) {
        const int lin = i * 256 + tid;
        const int d   = lin >> 4;
        const int s4  = (lin & 15) * 4;
        const half4 tv = *(const half4*)&T[d * 68 + s4];
        *(half4*)(qt_dst + (size_t)d * S_LEN + s4) = tv;
    }
}

// ---------- attention v7: barrier-free K-loop, K/V frags straight from global ----------
// Per wave: 64 q rows, all 2048 keys in 32 tiles of 64.
// S^T = K Q^T : A-frags loaded from Qh global (dense 16-line reads), B = Q regs.
// P -> per-wave LDS (pitch 72) -> A-frags for PV. V-frags from QhT global.
// l = row-sum of P via MFMA with B = ones -> lands in O's exact C-layout (no shuffles).
// No __syncthreads anywhere; waves free-run, pipes overlap across the 8 waves/CU.
__global__ __launch_bounds__(128, 2) void attn_v7_kernel(const _Float16* __restrict__ Qh,
                                                         const _Float16* __restrict__ QhT,
                                                         float* __restrict__ out) {
    __shared__ __align__(16) _Float16 Pbuf[2 * 64 * PP];   // per-wave P [64 q][64 kj], 2 x 9 KB

    const int tid  = threadIdx.x;
    const int w    = tid >> 6;
    const int lane = tid & 63;
    const int quad = lane >> 4;
    const int l15  = lane & 15;

    // XCD-grouping swizzle: all 16 WGs of one bh share blockIdx%8 -> same XCD's L2
    // (perf heuristic only; correctness independent of mapping).
    const int bi   = blockIdx.x;
    const int xcd  = bi & 7;
    const int slot = bi >> 3;              // 0..127
    const int bh   = xcd * 8 + (slot >> 4);
    const int qblk = slot & 15;
    const int q0   = qblk * 128 + w * 64;

    const _Float16* qh_bh = Qh + (size_t)bh * S_LEN * DH;
    const _Float16* qt_bh = QhT + (size_t)bh * DH * S_LEN;

    // Q register fragments (B-operand of S^T): lane holds Q[q=nch*16+l15][d=s*32+quad*8+j]
    half8 qreg[4][2];
    #pragma unroll
    for (int nch = 0; nch < 4; ++nch) {
        const _Float16* p = qh_bh + (size_t)(q0 + nch * 16 + l15) * DH + quad * 8;
        qreg[nch][0] = *(const half8*)p;
        qreg[nch][1] = *(const half8*)(p + 32);
    }

    // fixed per-column m = qs*||q||^2 (diagonal dominates; validated R1-R5)
    const float qs = 0.18033688011112042f;   // log2(e)/sqrt(64)
    float m_c[4];
    #pragma unroll
    for (int nch = 0; nch < 4; ++nch) {
        float part = 0.f;
        #pragma unroll
        for (int s = 0; s < 2; ++s)
            #pragma unroll
            for (int j = 0; j < 8; ++j) { const float x = (float)qreg[nch][s][j]; part += x * x; }
        part += __shfl_xor(part, 16, 64);
        part += __shfl_xor(part, 32, 64);
        m_c[nch] = qs * part;
    }

    half8 ones;
    #pragma unroll
    for (int j = 0; j < 8; ++j) ones[j] = (_Float16)1.0f;

    f32x4 O[4][4];                 // O[a=q-chunk][nch=d-chunk]
    #pragma unroll
    for (int a = 0; a < 4; ++a)
        #pragma unroll
        for (int n = 0; n < 4; ++n) O[a][n] = (f32x4){0.f, 0.f, 0.f, 0.f};
    f32x4 Lacc[4];                 // row-sums of P, same C-layout rows as O[a][*]
    #pragma unroll
    for (int a = 0; a < 4; ++a) Lacc[a] = (f32x4){0.f, 0.f, 0.f, 0.f};

    _Float16* Pw = &Pbuf[w * 64 * PP];
    // loop-invariant fragment base addresses
    const _Float16* knA = qh_bh + (size_t)(l15)*DH + quad * 8;          // + (t*64 + mch*16)*DH
    const _Float16* vtA = qt_bh + (size_t)(l15)*S_LEN + quad * 8;       // + nch*16*S_LEN + t*64 (+32)

    for (int t = 0; t < 32; ++t) {
        // ---- S^T = K Q^T, K-frags straight from global (L1/L2-resident) ----
        #pragma unroll
        for (int mch = 0; mch < 4; ++mch) {
            const _Float16* kp = knA + (size_t)(t * 64 + mch * 16) * DH;
            const half8 a0 = *(const half8*)kp;
            const half8 a1 = *(const half8*)(kp + 32);
            #pragma unroll
            for (int nch = 0; nch < 4; ++nch) {
                f32x4 acc = (f32x4){0.f, 0.f, 0.f, 0.f};
                acc = __builtin_amdgcn_mfma_f32_16x16x32_f16(a0, qreg[nch][0], acc, 0, 0, 0);
                acc = __builtin_amdgcn_mfma_f32_16x16x32_f16(a1, qreg[nch][1], acc, 0, 0, 0);
                const float p0 = __builtin_amdgcn_exp2f(__builtin_fmaf(acc[0], qs, -m_c[nch]));
                const float p1 = __builtin_amdgcn_exp2f(__builtin_fmaf(acc[1], qs, -m_c[nch]));
                const float p2 = __builtin_amdgcn_exp2f(__builtin_fmaf(acc[2], qs, -m_c[nch]));
                const float p3 = __builtin_amdgcn_exp2f(__builtin_fmaf(acc[3], qs, -m_c[nch]));
                const half4 hv = (half4){ (_Float16)p0, (_Float16)p1, (_Float16)p2, (_Float16)p3 };
                // P[q = nch*16+l15][kj = mch*16 + quad*4 + r]  (kj spans 0..63 -> needs PP>=64)
                *(half4*)&Pw[(nch * 16 + l15) * PP + mch * 16 + quad * 4] = hv;
            }
        }

        // ---- P back as A-frags (same-wave LDS roundtrip: lgkmcnt only) ----
        half8 pf[4][2];
        #pragma unroll
        for (int a = 0; a < 4; ++a) {
            pf[a][0] = *(const half8*)&Pw[(a * 16 + l15) * PP + quad * 8];
            pf[a][1] = *(const half8*)&Pw[(a * 16 + l15) * PP + 32 + quad * 8];
        }

        // ---- l += P * ones (row-sum in C-layout, no VALU) ----
        #pragma unroll
        for (int a = 0; a < 4; ++a) {
            Lacc[a] = __builtin_amdgcn_mfma_f32_16x16x32_f16(pf[a][0], ones, Lacc[a], 0, 0, 0);
            Lacc[a] = __builtin_amdgcn_mfma_f32_16x16x32_f16(pf[a][1], ones, Lacc[a], 0, 0, 0);
        }

        // ---- O += P V, V-frags straight from global QhT ----
        #pragma unroll
        for (int nch = 0; nch < 4; ++nch) {
            const _Float16* vp = vtA + (size_t)(nch * 16) * S_LEN + t * 64;
            const half8 v0 = *(const half8*)vp;
            const half8 v1 = *(const half8*)(vp + 32);
            #pragma unroll
            for (int a = 0; a < 4; ++a) {
                O[a][nch] = __builtin_amdgcn_mfma_f32_16x16x32_f16(pf[a][0], v0, O[a][nch], 0, 0, 0);
                O[a][nch] = __builtin_amdgcn_mfma_f32_16x16x32_f16(pf[a][1], v1, O[a][nch], 0, 0, 0);
            }
        }
    }

    // ---- epilogue: Lacc rows == O rows (both C-layout) -> direct divide, no shuffles ----
    const int b = bh >> 4, h = bh & 15;
    float* ob = out + (size_t)b * S_LEN * DM + h * DH;
    #pragma unroll
    for (int a = 0; a < 4; ++a) {
        float inv[4];
        #pragma unroll
        for (int r = 0; r < 4; ++r) inv[r] = 1.0f / Lacc[a][r];
        #pragma unroll
        for (int nch = 0; nch < 4; ++nch)
            #pragma unroll
            for (int r = 0; r < 4; ++r)
                ob[(size_t)(q0 + a * 16 + quad * 4 + r) * DM + nch * 16 + l15] = O[a][nch][r] * inv[r];
    }
}

extern "C" void kernel_launch(void* const* d_in, const int* in_sizes, int n_in,
                              void* d_out, int out_size, void* d_ws, size_t ws_size,
                              hipStream_t stream) {
    const float* Q = (const float*)d_in[0];   // K, V ignored per reference
    float* out = (float*)d_out;
    _Float16* Qh  = (_Float16*)d_ws;                      // 16 MiB
    _Float16* QhT = Qh + (size_t)NBH * S_LEN * DH;        // 16 MiB (ws >= 32 MiB verified R2-R5)
    preprocess_kernel<<<dim3(NBH * (S_LEN / 64)), dim3(256), 0, stream>>>(Q, Qh, QhT);
    attn_v7_kernel<<<dim3(NBH * (S_LEN / 128)), dim3(128), 0, stream>>>(Qh, QhT, out);
}